// Round 10
// baseline (263.515 us; speedup 1.0000x reference)
//
#include <hip/hip_runtime.h>
#include <math.h>

#define BB 32
#define GG 15
#define KK 2048
#define NB 480               // B*G blocks; co-resident (launch_bounds(256,2))
#define N1F 983040.0f
#define EPS 1e-5f

typedef _Float16 half8 __attribute__((ext_vector_type(8)));
typedef float f32x4 __attribute__((ext_vector_type(4)));

// ---- ws float offsets. Cross-block rule: write via atomicExch (contention-free
// slots), order via __syncthreads'/compiler vmcnt(0) drain before counter
// arrival, signal via write-once done flag (==1 vs 0xAA poison), read via
// agent-scope atomic loads. NO same-address atomicAdd chains (R6/R9 lesson).
#define WS_SRELP 0                      // [480][8]
#define WS_CENT  (WS_SRELP + NB*8)      // [480][4]
#define WS_BN1   (WS_CENT  + NB*4)      // [480][128]  S[64]|Q[64] per block
#define WS_H2A   (WS_BN1  + NB*128)     // [480][128]  position-indexed h2a
#define WS_H2B   (WS_H2A  + NB*128)     // [480][128]  position-indexed h2b
#define WS_H3A   (WS_H2B  + NB*128)     // [160][256]  pi-indexed
#define WS_H3B   (WS_H3A  + 160*256)    // [160][256]
#define GSREL    (WS_H3B  + 160*256)    // [30][8]
#define GBN1     (GSREL   + 240)        // [30][128]
#define G2A      (GBN1    + 3840)       // [30][256]  S[128]|Q[128]
#define G2B      (G2A     + 7680)       // [30][256]
#define G3A      (G2B     + 7680)       // [10][512]  S[256]|Q[256]
#define G3B      (G3A     + 5120)       // [10][512]
#define FSREL    (G3B     + 5120)       // [8]
#define FBN1     (FSREL   + 8)          // [128]
#define F2A      (FBN1    + 128)        // [256]
#define F2B      (F2A     + 256)        // [256]
#define F3A      (F2B     + 256)        // [512]
#define F3B      (F3A     + 512)        // [512]
// int offsets
#define CNT_GRP  (F3B + 512)            // [6][32]
#define CNT_SUP  (CNT_GRP + 192)        // [6]
#define CNT_DONE (CNT_SUP + 6)          // [6]  ==1 semantics
#define CNT_INIT (CNT_DONE + 6)         // 1    ==1 semantics
#define CNT_ZLEN 198                    // GRP+SUP zeroed by block 0

#define SMEMF 7936

__device__ const int SIDX[15] = {0,1,8, 2,4,6, 3,5,7, 9,11,13, 10,12,14};
__device__ const int INV[15]  = {0,1,3,6,4,7,5,8,2,9,12,10,13,11,14};

__device__ __forceinline__ int slotOf(int bid2){ return (bid2/15)*15 + INV[bid2%15]; }

__device__ __forceinline__ float wave_sum(float v){
    for (int off = 32; off; off >>= 1) v += __shfl_down(v, off, 64);
    return v;
}
__device__ __forceinline__ float aloadf(const float* p){
    return __hip_atomic_load(p, __ATOMIC_RELAXED, __HIP_MEMORY_SCOPE_AGENT);
}
__device__ __forceinline__ int aloadi(const int* p){
    return __hip_atomic_load(p, __ATOMIC_RELAXED, __HIP_MEMORY_SCOPE_AGENT);
}
// barrier pieces: arrival (detect group-last), super arrival, done set/wait.
__device__ __forceinline__ int bar_arrive(int* wsi, int idx, int gi, int* sflag){
    __syncthreads();                    // compiler drains all waves' VMEM here
    if (threadIdx.x == 0)
        sflag[0] = (atomicAdd(&wsi[CNT_GRP + idx*32 + gi], 1) == 15) ? 1 : 0;
    __syncthreads();
    return sflag[0];
}
__device__ __forceinline__ int bar_super(int* wsi, int idx, int ngrp, int* sflag){
    __syncthreads();
    if (threadIdx.x == 0)
        sflag[1] = (atomicAdd(&wsi[CNT_SUP + idx], 1) == ngrp - 1) ? 1 : 0;
    __syncthreads();
    return sflag[1];
}
__device__ __forceinline__ void bar_done(int* wsi, int idx){
    __syncthreads();
    if (threadIdx.x == 0) atomicExch(&wsi[CNT_DONE + idx], 1);
}
template<int SLP>
__device__ __forceinline__ void bar_wait(int* wsi, int idx){
    if (threadIdx.x == 0) {
        int g = 0;
        while (aloadi(&wsi[CNT_DONE + idx]) != 1 && ++g < 4000000)
            __builtin_amdgcn_s_sleep(SLP);
    }
    __syncthreads();
}

__global__ void __launch_bounds__(256, 2) mega(
        const float* __restrict__ x,
        const float* __restrict__ w00, const float* __restrict__ g00, const float* __restrict__ b00,
        const float* __restrict__ w01, const float* __restrict__ g01, const float* __restrict__ b01,
        const float* __restrict__ w10, const float* __restrict__ g10, const float* __restrict__ b10,
        const float* __restrict__ w11, const float* __restrict__ g11, const float* __restrict__ b11,
        const float* __restrict__ w20, const float* __restrict__ g20, const float* __restrict__ b20,
        const float* __restrict__ w21, const float* __restrict__ g21, const float* __restrict__ b21,
        float* __restrict__ ws, float* __restrict__ out) {
    __shared__ __align__(16) float smemf[SMEMF];
    float* xls  = smemf;
    float* redM = smemf + 6144; float* redN = smemf + 6400;
    float* redS = smemf + 6656; float* redQ = smemf + 6912;
    float* bcast= smemf + 7168;
    float* c2ls = smemf + 7184; float* c3ls = smemf + 7200;
    float* f2ls = smemf + 7204;   // 68
    float* vA   = smemf + 7272;   // 128
    float* f3ls = smemf + 7400;   // 132
    float* h3ls = smemf + 7532;   // 256
    int*   sflag= (int*)(smemf + 7916);
    int* wsi = (int*)ws;

    int bid = blockIdx.x, tid = threadIdx.x;
    int b_ = bid / GG, g_ = bid % GG;
    int wv = tid >> 6, lane = tid & 63, l15 = lane & 15, quad = lane >> 4;
    int gi = bid >> 4;                 // 30 groups of 16
    int gb = gi << 4;

    // ---- init: block 0 zeroes barrier counters behind init flag ----
    if (bid == 0) {
        if (tid < CNT_ZLEN) atomicExch(&wsi[CNT_GRP + tid], 0);
        __syncthreads();
        if (tid == 0) atomicExch(&wsi[CNT_INIT], 1);
    }
    if (tid == 0) {
        int g = 0;
        while (aloadi(&wsi[CNT_INIT]) != 1 && ++g < 4000000)
            __builtin_amdgcn_s_sleep(8);
    }
    __syncthreads();

    // ================= phase 1: x -> LDS; centroid + 3x3 moments ===============
    {
        const float4* xp4 = (const float4*)(x + (size_t)bid * KK * 3);
        float4* xls4 = (float4*)xls;
        #pragma unroll
        for (int i = 0; i < 6; i++) xls4[i*256 + tid] = xp4[i*256 + tid];
        __syncthreads();
        float m[9] = {0,0,0,0,0,0,0,0,0};
        float a[24];
        const float* bp = &xls[tid*24];
        #pragma unroll
        for (int i = 0; i < 6; i++)
            *reinterpret_cast<float4*>(&a[i*4]) = *reinterpret_cast<const float4*>(&bp[i*4]);
        #pragma unroll
        for (int p = 0; p < 8; p++) {
            float ax=a[p*3], ay=a[p*3+1], az=a[p*3+2];
            m[0]+=ax; m[1]+=ay; m[2]+=az;
            m[3]=fmaf(ax,ax,m[3]); m[4]=fmaf(ay,ay,m[4]); m[5]=fmaf(az,az,m[5]);
            m[6]=fmaf(ax,ay,m[6]); m[7]=fmaf(ax,az,m[7]); m[8]=fmaf(ay,az,m[8]);
        }
        #pragma unroll
        for (int q = 0; q < 9; q++) {
            float v = wave_sum(m[q]);
            if (lane == 0) redM[q*4 + wv] = v;
        }
        __syncthreads();
        if (tid == 0) {
            float t[9];
            #pragma unroll
            for (int q = 0; q < 9; q++) t[q] = redM[q*4]+redM[q*4+1]+redM[q*4+2]+redM[q*4+3];
            float c0 = t[0]/KK, c1 = t[1]/KK, c2 = t[2]/KK;
            bcast[0]=c0; bcast[1]=c1; bcast[2]=c2;
            out[8192 + b_*(67*GG) + 0*GG + g_] = c0;
            out[8192 + b_*(67*GG) + 1*GG + g_] = c1;
            out[8192 + b_*(67*GG) + 2*GG + g_] = c2;
            atomicExch(&ws[WS_CENT + bid*4 + 0], c0);
            atomicExch(&ws[WS_CENT + bid*4 + 1], c1);
            atomicExch(&ws[WS_CENT + bid*4 + 2], c2);
            atomicExch(&ws[WS_SRELP + bid*8 + 0], t[3] - KK*c0*c0);
            atomicExch(&ws[WS_SRELP + bid*8 + 1], t[4] - KK*c1*c1);
            atomicExch(&ws[WS_SRELP + bid*8 + 2], t[5] - KK*c2*c2);
            atomicExch(&ws[WS_SRELP + bid*8 + 3], t[6] - KK*c0*c1);
            atomicExch(&ws[WS_SRELP + bid*8 + 4], t[7] - KK*c0*c2);
            atomicExch(&ws[WS_SRELP + bid*8 + 5], t[8] - KK*c1*c2);
        }
    }
    // ---- barrier 1 (idx 0) + hierarchical SREL reduce ----
    if (bar_arrive(wsi, 0, gi, sflag)) {
        if (tid < 96) {
            int s = tid/6, q = tid%6;
            redS[tid] = aloadf(&ws[WS_SRELP + (gb+s)*8 + q]);
        }
        __syncthreads();
        if (tid < 6) {
            float acc = 0.f;
            #pragma unroll
            for (int s = 0; s < 16; s++) acc += redS[s*6+tid];
            atomicExch(&ws[GSREL + gi*8 + tid], acc);
        }
        if (bar_super(wsi, 0, 30, sflag)) {
            if (tid < 180) {
                int s = tid/6, q = tid%6;
                redS[tid] = aloadf(&ws[GSREL + s*8 + q]);
            }
            __syncthreads();
            if (tid < 6) {
                float acc = 0.f;
                #pragma unroll
                for (int s = 0; s < 30; s++) acc += redS[s*6+tid];
                atomicExch(&ws[FSREL + tid], acc);
            }
            bar_done(wsi, 0);
        }
    }
    bar_wait<8>(wsi, 0);

    // ---- read FSREL + per-b c2/c3 ----
    if (tid < 6) bcast[3+tid] = aloadf(&ws[FSREL + tid]) / N1F;
    if (tid >= 64 && tid < 79) {
        int t2 = tid-64, s = t2/3, i = t2%3;
        float acc = 0.f;
        #pragma unroll
        for (int j = 0; j < 3; j++)
            acc += aloadf(&ws[WS_CENT + (b_*GG + SIDX[s*3+j])*4 + i]);
        c2ls[t2] = acc * (1.f/3.f);
    }
    __syncthreads();
    if (tid < 3) {
        float a = 0.f;
        for (int s = 0; s < 5; s++) a += c2ls[s*3+tid];
        c3ls[tid] = a * 0.2f;
    }
    __syncthreads();
    float c0 = bcast[0], c1 = bcast[1], c2v = bcast[2];
    float S00=bcast[3], S11=bcast[4], S22=bcast[5], S01=bcast[6], S02=bcast[7], S12=bcast[8];

    // ================= phase 2: barrier-free MFMA over 2048 k ==================
    half8 afA[4], afB[4];
    #pragma unroll
    for (int t = 0; t < 4; t++)
        #pragma unroll
        for (int j = 0; j < 8; j++) {
            afA[t][j] = (_Float16)w01[(t*16 + l15)*64 + quad*8 + j];
            afB[t][j] = (_Float16)w01[(t*16 + l15)*64 + 32 + quad*8 + j];
        }
    float wa0[8], wa1[8], wa2[8], ba[8], wb0[8], wb1[8], wb2[8], bb[8];
    #pragma unroll
    for (int j = 0; j < 8; j++) {
        int cA = quad*8 + j;
        float u0=w00[cA*3+0], u1=w00[cA*3+1], u2=w00[cA*3+2];
        float var = u0*u0*S00 + u1*u1*S11 + u2*u2*S22
                  + 2.f*(u0*u1*S01 + u0*u2*S02 + u1*u2*S12);
        float a1 = g00[cA]*rsqrtf(var + EPS);
        wa0[j]=a1*u0; wa1[j]=a1*u1; wa2[j]=a1*u2; ba[j]=b00[cA];
        int cB = cA + 32;
        float v0=w00[cB*3+0], v1=w00[cB*3+1], v2=w00[cB*3+2];
        float varB = v0*v0*S00 + v1*v1*S11 + v2*v2*S22
                   + 2.f*(v0*v1*S01 + v0*v2*S02 + v1*v2*S12);
        float a1B = g00[cB]*rsqrtf(varB + EPS);
        wb0[j]=a1B*v0; wb1[j]=a1B*v1; wb2[j]=a1B*v2; bb[j]=b00[cB];
    }
    float mx[16], mn[16], sm[16], sq[16];
    #pragma unroll
    for (int s = 0; s < 16; s++) { mx[s]=-1e30f; mn[s]=1e30f; sm[s]=0.f; sq[s]=0.f; }

    for (int it = 0; it < 32; it++) {
        int k = it*64 + wv*16 + l15;
        float r0 = xls[k*3+0]-c0, r1 = xls[k*3+1]-c1, r2 = xls[k*3+2]-c2v;
        half8 bf0, bf1;
        #pragma unroll
        for (int j = 0; j < 8; j++) {
            float pA = fmaf(wa0[j],r0, fmaf(wa1[j],r1, fmaf(wa2[j],r2, ba[j])));
            bf0[j] = (_Float16)fmaxf(pA, 0.f);
            float pB = fmaf(wb0[j],r0, fmaf(wb1[j],r1, fmaf(wb2[j],r2, bb[j])));
            bf1[j] = (_Float16)fmaxf(pB, 0.f);
        }
        #pragma unroll
        for (int t = 0; t < 4; t++) {
            f32x4 acc = {0.f,0.f,0.f,0.f};
            acc = __builtin_amdgcn_mfma_f32_16x16x32_f16(afA[t], bf0, acc, 0, 0, 0);
            acc = __builtin_amdgcn_mfma_f32_16x16x32_f16(afB[t], bf1, acc, 0, 0, 0);
            #pragma unroll
            for (int r = 0; r < 4; r++) {
                float h = acc[r];
                int s = t*4 + r;
                mx[s]=fmaxf(mx[s],h); mn[s]=fminf(mn[s],h);
                sm[s]+=h;             sq[s]=fmaf(h,h,sq[s]);
            }
        }
    }
    #pragma unroll
    for (int m = 1; m < 16; m <<= 1) {
        #pragma unroll
        for (int s = 0; s < 16; s++) {
            mx[s] = fmaxf(mx[s], __shfl_xor(mx[s], m, 64));
            mn[s] = fminf(mn[s], __shfl_xor(mn[s], m, 64));
            sm[s] += __shfl_xor(sm[s], m, 64);
            sq[s] += __shfl_xor(sq[s], m, 64);
        }
    }
    __syncthreads();
    if (l15 == 0) {
        #pragma unroll
        for (int t = 0; t < 4; t++)
            #pragma unroll
            for (int r = 0; r < 4; r++) {
                int o = t*16 + quad*4 + r;
                redM[wv*64+o]=mx[t*4+r]; redN[wv*64+o]=mn[t*4+r];
                redS[wv*64+o]=sm[t*4+r]; redQ[wv*64+o]=sq[t*4+r];
            }
    }
    __syncthreads();
    float Mreg = -1e30f, Nreg = 1e30f;
    if (tid < 64) {
        float S=0.f, Q=0.f;
        #pragma unroll
        for (int w = 0; w < 4; w++) {
            Mreg = fmaxf(Mreg, redM[w*64+tid]); Nreg = fminf(Nreg, redN[w*64+tid]);
            S += redS[w*64+tid];               Q += redQ[w*64+tid];
        }
        atomicExch(&ws[WS_BN1 + bid*128 + tid], S);
        atomicExch(&ws[WS_BN1 + bid*128 + 64 + tid], Q);
    }
    // ---- barrier 2 (idx 1) + BN1 stat reduce ----
    if (bar_arrive(wsi, 1, gi, sflag)) {
        if (tid < 128) {
            float acc = 0.f;
            #pragma unroll
            for (int s = 0; s < 16; s++) acc += aloadf(&ws[WS_BN1 + (gb+s)*128 + tid]);
            atomicExch(&ws[GBN1 + gi*128 + tid], acc);
        }
        if (bar_super(wsi, 1, 30, sflag)) {
            if (tid < 128) {
                float acc = 0.f;
                #pragma unroll
                for (int s = 0; s < 30; s++) acc += aloadf(&ws[GBN1 + s*128 + tid]);
                atomicExch(&ws[FBN1 + tid], acc);
            }
            bar_done(wsi, 1);
        }
    }
    bar_wait<8>(wsi, 1);

    int p_ = INV[g_];

    // ---- T0: f2 column (lf1 from own Mreg/Nreg + final BN1 stats) ----
    if (tid < 64) {
        float SM = aloadf(&ws[FBN1 + tid]);
        float SQ = aloadf(&ws[FBN1 + 64 + tid]);
        float mean = SM / N1F;
        float var  = SQ / N1F - mean*mean;
        float s1 = g01[tid]*rsqrtf(var + EPS);
        float t1 = b01[tid] - mean*s1;
        float val = fmaxf(fmaf(s1, (s1 >= 0.f) ? Mreg : Nreg, t1), 0.f);
        f2ls[3+tid] = val;
        out[8192 + b_*(67*GG) + (3+tid)*GG + g_] = val;
    } else if (tid < 67) {
        int i = tid - 64;
        f2ls[i] = bcast[i] - c2ls[(p_/3)*3 + i];
    }
    __syncthreads();

    // ---- phase A: h2a = w10 @ f2, coalesced GEMV (lanes over c) ----
    {
        #pragma unroll 4
        for (int oo = 0; oo < 32; oo++) {
            int o = wv*32 + oo;
            float p = w10[o*67 + lane] * f2ls[lane];
            if (lane < 3) p = fmaf(w10[o*67 + 64 + lane], f2ls[64 + lane], p);
            p = wave_sum(p);
            if (lane == 0) vA[o] = p;
        }
        __syncthreads();
        if (tid < 128) atomicExch(&ws[WS_H2A + (b_*GG + p_)*128 + tid], vA[tid]);
    }
    // ---- barrier 3 (idx 2) + S2A stat reduce from H2A slots ----
    if (bar_arrive(wsi, 2, gi, sflag)) {
        int o = tid & 127, isQ = tid >> 7;
        float acc = 0.f;
        #pragma unroll
        for (int s = 0; s < 16; s++) {
            float h = aloadf(&ws[WS_H2A + slotOf(gb+s)*128 + o]);
            acc += isQ ? h*h : h;
        }
        atomicExch(&ws[G2A + gi*256 + tid], acc);
        if (bar_super(wsi, 2, 30, sflag)) {
            float a2 = 0.f;
            #pragma unroll
            for (int s = 0; s < 30; s++) a2 += aloadf(&ws[G2A + s*256 + tid]);
            atomicExch(&ws[F2A + tid], a2);
            bar_done(wsi, 2);
        }
    }
    bar_wait<4>(wsi, 2);

    // ---- phase B: BN2a; h2b = w11 @ v, coalesced GEMV ----
    {
        if (tid < 128) {
            float mean = aloadf(&ws[F2A + tid]) / 480.f;
            float var  = aloadf(&ws[F2A + 128 + tid]) / 480.f - mean*mean;
            float s2 = g10[tid]*rsqrtf(var+EPS), t2 = b10[tid] - mean*s2;
            vA[tid] = fmaxf(fmaf(s2, vA[tid], t2), 0.f);
        }
        __syncthreads();
        #pragma unroll 4
        for (int oo = 0; oo < 32; oo++) {
            int o = wv*32 + oo;
            float p = fmaf(w11[o*128 + lane], vA[lane],
                           w11[o*128 + 64 + lane] * vA[64 + lane]);
            p = wave_sum(p);
            if (lane == 0) atomicExch(&ws[WS_H2B + (b_*GG + p_)*128 + o], p);
        }
    }
    // ---- barrier 4 (idx 3) + S2B stat reduce ----
    if (bar_arrive(wsi, 3, gi, sflag)) {
        int o = tid & 127, isQ = tid >> 7;
        float acc = 0.f;
        #pragma unroll
        for (int s = 0; s < 16; s++) {
            float h = aloadf(&ws[WS_H2B + slotOf(gb+s)*128 + o]);
            acc += isQ ? h*h : h;
        }
        atomicExch(&ws[G2B + gi*256 + tid], acc);
        if (bar_super(wsi, 3, 30, sflag)) {
            float a2 = 0.f;
            #pragma unroll
            for (int s = 0; s < 30; s++) a2 += aloadf(&ws[G2B + s*256 + tid]);
            atomicExch(&ws[F2B + tid], a2);
            bar_done(wsi, 3);
        }
    }
    if (g_ >= 5) return;              // non-participants exit after arrival+duties
    bar_wait<4>(wsi, 3);

    int pi = b_*5 + g_;
    int gi2 = pi >> 4, gb2 = gi2 << 4;

    // ---- phase C: lf2 + feats3; h3a = w20 @ f3, coalesced GEMV ----
    {
        int s5 = g_;
        if (tid < 128) {
            float mean = aloadf(&ws[F2B + tid]) / 480.f;
            float var  = aloadf(&ws[F2B + 128 + tid]) / 480.f - mean*mean;
            float s3 = g11[tid]*rsqrtf(var+EPS), t3 = b11[tid] - mean*s3;
            float m = -1e30f;
            #pragma unroll
            for (int j = 0; j < 3; j++) {
                float hv = aloadf(&ws[WS_H2B + (b_*GG + s5*3 + j)*128 + tid]);
                m = fmaxf(m, fmaxf(fmaf(s3, hv, t3), 0.f));
            }
            f3ls[3+tid] = m;
        } else if (tid < 131) {
            int i = tid - 128;
            f3ls[i] = c2ls[s5*3+i] - c3ls[i];
        }
        __syncthreads();
        #pragma unroll 4
        for (int oo = 0; oo < 64; oo++) {
            int o = wv*64 + oo;
            float p = fmaf(w20[o*131 + lane], f3ls[lane],
                           w20[o*131 + 64 + lane] * f3ls[64 + lane]);
            if (lane < 3) p = fmaf(w20[o*131 + 128 + lane], f3ls[128 + lane], p);
            p = wave_sum(p);
            if (lane == 0) h3ls[o] = p;
        }
        __syncthreads();
        atomicExch(&ws[WS_H3A + pi*256 + tid], h3ls[tid]);
    }
    // ---- barrier 5 (idx 4, 160 participants, 10 groups) + S3A reduce ----
    if (bar_arrive(wsi, 4, gi2, sflag)) {
        float aS = 0.f, aQ = 0.f;
        #pragma unroll
        for (int s = 0; s < 16; s++) {
            float h = aloadf(&ws[WS_H3A + (gb2+s)*256 + tid]);
            aS += h; aQ = fmaf(h, h, aQ);
        }
        atomicExch(&ws[G3A + gi2*512 + tid], aS);
        atomicExch(&ws[G3A + gi2*512 + 256 + tid], aQ);
        if (bar_super(wsi, 4, 10, sflag)) {
            float sS = 0.f, sQ = 0.f;
            #pragma unroll
            for (int s = 0; s < 10; s++) {
                sS += aloadf(&ws[G3A + s*512 + tid]);
                sQ += aloadf(&ws[G3A + s*512 + 256 + tid]);
            }
            atomicExch(&ws[F3A + tid], sS);
            atomicExch(&ws[F3A + 256 + tid], sQ);
            bar_done(wsi, 4);
        }
    }
    bar_wait<4>(wsi, 4);

    // ---- phase D: BN3a; h3b = w21 @ v, coalesced GEMV ----
    {
        float mean = aloadf(&ws[F3A + tid]) / 160.f;
        float var  = aloadf(&ws[F3A + 256 + tid]) / 160.f - mean*mean;
        float s4 = g20[tid]*rsqrtf(var+EPS), t4 = b20[tid] - mean*s4;
        h3ls[tid] = fmaxf(fmaf(s4, h3ls[tid], t4), 0.f);
        __syncthreads();
        #pragma unroll 2
        for (int oo = 0; oo < 64; oo++) {
            int o = wv*64 + oo;
            float p = fmaf(w21[o*256 + lane], h3ls[lane],
                     fmaf(w21[o*256 + 64 + lane], h3ls[64 + lane],
                     fmaf(w21[o*256 + 128 + lane], h3ls[128 + lane],
                          w21[o*256 + 192 + lane] * h3ls[192 + lane])));
            p = wave_sum(p);
            if (lane == 0) atomicExch(&ws[WS_H3B + pi*256 + o], p);
        }
    }
    // ---- barrier 6 (idx 5) + S3B reduce ----
    if (bar_arrive(wsi, 5, gi2, sflag)) {
        float aS = 0.f, aQ = 0.f;
        #pragma unroll
        for (int s = 0; s < 16; s++) {
            float h = aloadf(&ws[WS_H3B + (gb2+s)*256 + tid]);
            aS += h; aQ = fmaf(h, h, aQ);
        }
        atomicExch(&ws[G3B + gi2*512 + tid], aS);
        atomicExch(&ws[G3B + gi2*512 + 256 + tid], aQ);
        if (bar_super(wsi, 5, 10, sflag)) {
            float sS = 0.f, sQ = 0.f;
            #pragma unroll
            for (int s = 0; s < 10; s++) {
                sS += aloadf(&ws[G3B + s*512 + tid]);
                sQ += aloadf(&ws[G3B + s*512 + 256 + tid]);
            }
            atomicExch(&ws[F3B + tid], sS);
            atomicExch(&ws[F3B + 256 + tid], sQ);
            bar_done(wsi, 5);
        }
    }
    if (g_ != 0) return;
    bar_wait<4>(wsi, 5);

    // ---- phase E (32 blocks): gf = max_s5 relu(BN(h3b)) ----
    {
        float mean = aloadf(&ws[F3B + tid]) / 160.f;
        float var  = aloadf(&ws[F3B + 256 + tid]) / 160.f - mean*mean;
        float s5c = g21[tid]*rsqrtf(var+EPS), t5 = b21[tid] - mean*s5c;
        float m = -1e30f;
        #pragma unroll
        for (int jj = 0; jj < 5; jj++) {
            float hv = aloadf(&ws[WS_H3B + (b_*5 + jj)*256 + tid]);
            m = fmaxf(m, fmaxf(fmaf(s5c, hv, t5), 0.f));
        }
        out[b_*256 + tid] = m;
    }
}

extern "C" void kernel_launch(void* const* d_in, const int* in_sizes, int n_in,
                              void* d_out, int out_size, void* d_ws, size_t ws_size,
                              hipStream_t stream) {
    (void)in_sizes; (void)n_in; (void)out_size; (void)ws_size;
    const float* x   = (const float*)d_in[0];
    const float* w00 = (const float*)d_in[1];
    const float* g00 = (const float*)d_in[2];
    const float* b00 = (const float*)d_in[3];
    const float* w01 = (const float*)d_in[4];
    const float* g01 = (const float*)d_in[5];
    const float* b01 = (const float*)d_in[6];
    const float* w10 = (const float*)d_in[7];
    const float* g10 = (const float*)d_in[8];
    const float* b10 = (const float*)d_in[9];
    const float* w11 = (const float*)d_in[10];
    const float* g11 = (const float*)d_in[11];
    const float* b11 = (const float*)d_in[12];
    const float* w20 = (const float*)d_in[13];
    const float* g20 = (const float*)d_in[14];
    const float* b20 = (const float*)d_in[15];
    const float* w21 = (const float*)d_in[16];
    const float* g21 = (const float*)d_in[17];
    const float* b21 = (const float*)d_in[18];
    float* out = (float*)d_out;
    float* ws  = (float*)d_ws;

    mega<<<NB, 256, 0, stream>>>(x, w00,g00,b00, w01,g01,b01, w10,g10,b10,
                                 w11,g11,b11, w20,g20,b20, w21,g21,b21, ws, out);
}

// Round 11
// 245.907 us; speedup vs baseline: 1.0716x; 1.0716x over previous
//
#include <hip/hip_runtime.h>
#include <math.h>

#define BB 32
#define GG 15
#define KK 2048
#define NB 480               // B*G blocks; co-resident (launch_bounds(256,2))
#define N1F 983040.0f
#define EPS 1e-5f

typedef _Float16 half8 __attribute__((ext_vector_type(8)));
typedef float f32x4 __attribute__((ext_vector_type(4)));

// ---- ws float offsets. Cross-block rule: producers write via atomicExch
// (reaches coherent L3; R3-R9 proven), sync via counter+write-once done flag,
// consumers read slot data with PLAIN loads (first touch after sync -> L2 miss
// -> L3 -> correct; no L1/L2 copy can exist: kernel-start acquire invalidated
// caches and each slot line has exactly one reader, post-sync). Small final
// stats still read via agent atomic loads.
#define WS_SRELP 0                      // [480][8]
#define WS_CENT  3840                   // [480][4]
#define WS_MAXV  5760                   // [480][64]
#define WS_MINV  36480                  // [480][64]
#define WS_BN1   67200                  // [480][128] S|Q
#define GSREL    128640                 // [30][8]
#define GBN1     128880                 // [30][128]
#define FSREL    132720                 // [8]
#define FBN1     132728                 // [128]
#define WS_P2A   132864                 // [32][256]  S[128]|Q[128]
#define WS_P2B   141056                 // [32][256]
#define WS_P3A   149248                 // [32][512]  S[256]|Q[256]
#define WS_P3B   165632                 // [32][512]
// int offsets
#define CNT_GRP  182016                 // [6][32]
#define CNT_SUP  182208                 // [6]  (mini-barriers use SUP directly)
#define CNT_DONE 182214                 // [6]  ==1 semantics
#define CNT_INIT 182220                 // 1    ==1 semantics
#define CNT_ZLEN 198                    // GRP+SUP zeroed by block 0

// ---- LDS (floats): 7424 = 29696 B -> 2 blocks/CU ----
// head: xls@0(6144) redM@6144 redN@6400 redS@6656 redQ@6912(..7168)
// tail: f2s@0[15][68] h2a@1024[15][132] h2b@3008[15][132] f3s@4992[5][132]
//       h3a@0[5][260] (after B) sC3@1536(256) tC3@1792(256)
//       sA@6952 tA@7016 sC@7080(128) tC@7208(128)
// common: bcast@7344(16) c2ls@7360(16) c3ls@7376(4) sflag@7380
#define SMEMF 7424

__device__ const int SIDX[15] = {0,1,8, 2,4,6, 3,5,7, 9,11,13, 10,12,14};
__device__ const int INV[15]  = {0,1,3,6,4,7,5,8,2,9,12,10,13,11,14};

__device__ __forceinline__ float wave_sum(float v){
    for (int off = 32; off; off >>= 1) v += __shfl_down(v, off, 64);
    return v;
}
__device__ __forceinline__ float aloadf(const float* p){
    return __hip_atomic_load(p, __ATOMIC_RELAXED, __HIP_MEMORY_SCOPE_AGENT);
}
__device__ __forceinline__ int aloadi(const int* p){
    return __hip_atomic_load(p, __ATOMIC_RELAXED, __HIP_MEMORY_SCOPE_AGENT);
}
template<int SLP>
__device__ __forceinline__ void poll1(const int* p){
    if (threadIdx.x == 0) {
        int g = 0;
        while (aloadi(p) != 1 && ++g < 4000000) __builtin_amdgcn_s_sleep(SLP);
    }
    __syncthreads();
    asm volatile("" ::: "memory");
}
// mini barrier among n blocks: single counter + done flag
template<int SLP>
__device__ __forceinline__ void minibar(int* wsi, int idx, int n){
    __syncthreads();
    if (threadIdx.x == 0) {
        if (atomicAdd(&wsi[CNT_SUP + idx], 1) == n - 1)
            atomicExch(&wsi[CNT_DONE + idx], 1);
    }
    poll1<SLP>(&wsi[CNT_DONE + idx]);
}

__global__ void __launch_bounds__(256, 2) mega(
        const float* __restrict__ x,
        const float* __restrict__ w00, const float* __restrict__ g00, const float* __restrict__ b00,
        const float* __restrict__ w01, const float* __restrict__ g01, const float* __restrict__ b01,
        const float* __restrict__ w10, const float* __restrict__ g10, const float* __restrict__ b10,
        const float* __restrict__ w11, const float* __restrict__ g11, const float* __restrict__ b11,
        const float* __restrict__ w20, const float* __restrict__ g20, const float* __restrict__ b20,
        const float* __restrict__ w21, const float* __restrict__ g21, const float* __restrict__ b21,
        float* __restrict__ ws, float* __restrict__ out) {
    __shared__ __align__(16) float smemf[SMEMF];
    float* xls  = smemf;
    float* redM = smemf + 6144; float* redN = smemf + 6400;
    float* redS = smemf + 6656; float* redQ = smemf + 6912;
    float* f2s  = smemf;          // tail aliases
    float* h2a  = smemf + 1024;   // [15][132]
    float* h2b  = smemf + 3008;   // [15][132]
    float* f3s  = smemf + 4992;   // [5][132]
    float* h3a  = smemf;          // [5][260] (after phase B)
    float* sC3  = smemf + 1536;  float* tC3 = smemf + 1792;
    float* sA   = smemf + 6952;  float* tA  = smemf + 7016;
    float* sC   = smemf + 7080;  float* tC  = smemf + 7208;
    float* bcast= smemf + 7344;
    float* c2ls = smemf + 7360;  float* c3ls= smemf + 7376;
    int*   sflag= (int*)(smemf + 7380);
    int* wsi = (int*)ws;

    int bid = blockIdx.x, tid = threadIdx.x;
    int b_ = bid / GG, g_ = bid % GG;
    int wv = tid >> 6, lane = tid & 63, l15 = lane & 15, quad = lane >> 4;
    int gi = bid >> 4, gb = gi << 4;   // 30 groups of 16

    // ---- init: block 0 zeroes counters behind init flag ----
    if (bid == 0) {
        if (tid < CNT_ZLEN) atomicExch(&wsi[CNT_GRP + tid], 0);
        __syncthreads();
        if (tid == 0) atomicExch(&wsi[CNT_INIT], 1);
    }
    poll1<8>(&wsi[CNT_INIT]);

    // ================= phase 1: x -> LDS; centroid + 3x3 moments ===============
    {
        const float4* xp4 = (const float4*)(x + (size_t)bid * KK * 3);
        float4* xls4 = (float4*)xls;
        #pragma unroll
        for (int i = 0; i < 6; i++) xls4[i*256 + tid] = xp4[i*256 + tid];
        __syncthreads();
        float m[9] = {0,0,0,0,0,0,0,0,0};
        float a[24];
        const float* bp = &xls[tid*24];
        #pragma unroll
        for (int i = 0; i < 6; i++)
            *reinterpret_cast<float4*>(&a[i*4]) = *reinterpret_cast<const float4*>(&bp[i*4]);
        #pragma unroll
        for (int p = 0; p < 8; p++) {
            float ax=a[p*3], ay=a[p*3+1], az=a[p*3+2];
            m[0]+=ax; m[1]+=ay; m[2]+=az;
            m[3]=fmaf(ax,ax,m[3]); m[4]=fmaf(ay,ay,m[4]); m[5]=fmaf(az,az,m[5]);
            m[6]=fmaf(ax,ay,m[6]); m[7]=fmaf(ax,az,m[7]); m[8]=fmaf(ay,az,m[8]);
        }
        #pragma unroll
        for (int q = 0; q < 9; q++) {
            float v = wave_sum(m[q]);
            if (lane == 0) redM[q*4 + wv] = v;
        }
        __syncthreads();
        if (tid == 0) {
            float t[9];
            #pragma unroll
            for (int q = 0; q < 9; q++) t[q] = redM[q*4]+redM[q*4+1]+redM[q*4+2]+redM[q*4+3];
            float c0 = t[0]/KK, c1 = t[1]/KK, c2 = t[2]/KK;
            bcast[0]=c0; bcast[1]=c1; bcast[2]=c2;
            out[8192 + b_*(67*GG) + 0*GG + g_] = c0;
            out[8192 + b_*(67*GG) + 1*GG + g_] = c1;
            out[8192 + b_*(67*GG) + 2*GG + g_] = c2;
            atomicExch(&ws[WS_CENT + bid*4 + 0], c0);
            atomicExch(&ws[WS_CENT + bid*4 + 1], c1);
            atomicExch(&ws[WS_CENT + bid*4 + 2], c2);
            atomicExch(&ws[WS_SRELP + bid*8 + 0], t[3] - KK*c0*c0);
            atomicExch(&ws[WS_SRELP + bid*8 + 1], t[4] - KK*c1*c1);
            atomicExch(&ws[WS_SRELP + bid*8 + 2], t[5] - KK*c2*c2);
            atomicExch(&ws[WS_SRELP + bid*8 + 3], t[6] - KK*c0*c1);
            atomicExch(&ws[WS_SRELP + bid*8 + 4], t[7] - KK*c0*c2);
            atomicExch(&ws[WS_SRELP + bid*8 + 5], t[8] - KK*c1*c2);
        }
    }
    // ---- grid barrier 1 + SREL reduce (plain loads inside) ----
    {
        __syncthreads();
        if (tid == 0)
            sflag[0] = (atomicAdd(&wsi[CNT_GRP + 0*32 + gi], 1) == 15) ? 1 : 0;
        __syncthreads();
        if (sflag[0]) {
            if (tid < 128) redS[tid] = ws[WS_SRELP + (gb + (tid>>3))*8 + (tid&7)];
            __syncthreads();
            if (tid < 6) {
                float acc = 0.f;
                #pragma unroll
                for (int s = 0; s < 16; s++) acc += redS[s*8 + tid];
                atomicExch(&ws[GSREL + gi*8 + tid], acc);
            }
            __syncthreads();
            if (tid == 0)
                sflag[1] = (atomicAdd(&wsi[CNT_SUP + 0], 1) == 29) ? 1 : 0;
            __syncthreads();
            if (sflag[1]) {
                if (tid < 240) redS[tid] = ws[GSREL + tid];
                __syncthreads();
                if (tid < 6) {
                    float acc = 0.f;
                    #pragma unroll
                    for (int s = 0; s < 30; s++) acc += redS[s*8 + tid];
                    atomicExch(&ws[FSREL + tid], acc);
                }
                __syncthreads();
                if (tid == 0) atomicExch(&wsi[CNT_DONE + 0], 1);
            }
        }
        poll1<8>(&wsi[CNT_DONE + 0]);
    }
    if (tid < 6) bcast[3+tid] = aloadf(&ws[FSREL + tid]) / N1F;
    if (tid >= 64 && tid < 109) {
        int t2 = tid-64, s = t2/3, i = t2%3;      // c2 for own b (15 entries via 45 thr)
        if (i == 0) {
            float a0=0,a1=0,a2=0;
            #pragma unroll
            for (int j = 0; j < 3; j++) {
                int gg = SIDX[s*3+j];
                a0 += aloadf(&ws[WS_CENT + (b_*GG+gg)*4 + 0]);
                a1 += aloadf(&ws[WS_CENT + (b_*GG+gg)*4 + 1]);
                a2 += aloadf(&ws[WS_CENT + (b_*GG+gg)*4 + 2]);
            }
            c2ls[s*3+0]=a0*(1.f/3.f); c2ls[s*3+1]=a1*(1.f/3.f); c2ls[s*3+2]=a2*(1.f/3.f);
        }
    }
    __syncthreads();
    if (tid < 3) {
        float a = 0.f;
        for (int s = 0; s < 5; s++) a += c2ls[s*3+tid];
        c3ls[tid] = a * 0.2f;
    }
    __syncthreads();
    float c0 = bcast[0], c1 = bcast[1], c2v = bcast[2];
    float S00=bcast[3], S11=bcast[4], S22=bcast[5], S01=bcast[6], S02=bcast[7], S12=bcast[8];

    // ================= phase 2: barrier-free MFMA over 2048 k ==================
    half8 afA[4], afB[4];
    #pragma unroll
    for (int t = 0; t < 4; t++)
        #pragma unroll
        for (int j = 0; j < 8; j++) {
            afA[t][j] = (_Float16)w01[(t*16 + l15)*64 + quad*8 + j];
            afB[t][j] = (_Float16)w01[(t*16 + l15)*64 + 32 + quad*8 + j];
        }
    float wa0[8], wa1[8], wa2[8], ba[8], wb0[8], wb1[8], wb2[8], bb[8];
    #pragma unroll
    for (int j = 0; j < 8; j++) {
        int cA = quad*8 + j;
        float u0=w00[cA*3+0], u1=w00[cA*3+1], u2=w00[cA*3+2];
        float var = u0*u0*S00 + u1*u1*S11 + u2*u2*S22
                  + 2.f*(u0*u1*S01 + u0*u2*S02 + u1*u2*S12);
        float a1 = g00[cA]*rsqrtf(var + EPS);
        wa0[j]=a1*u0; wa1[j]=a1*u1; wa2[j]=a1*u2; ba[j]=b00[cA];
        int cB = cA + 32;
        float v0=w00[cB*3+0], v1=w00[cB*3+1], v2=w00[cB*3+2];
        float varB = v0*v0*S00 + v1*v1*S11 + v2*v2*S22
                   + 2.f*(v0*v1*S01 + v0*v2*S02 + v1*v2*S12);
        float a1B = g00[cB]*rsqrtf(varB + EPS);
        wb0[j]=a1B*v0; wb1[j]=a1B*v1; wb2[j]=a1B*v2; bb[j]=b00[cB];
    }
    float mx[16], mn[16], sm[16], sq[16];
    #pragma unroll
    for (int s = 0; s < 16; s++) { mx[s]=-1e30f; mn[s]=1e30f; sm[s]=0.f; sq[s]=0.f; }

    for (int it = 0; it < 32; it++) {
        int k = it*64 + wv*16 + l15;
        float r0 = xls[k*3+0]-c0, r1 = xls[k*3+1]-c1, r2 = xls[k*3+2]-c2v;
        half8 bf0, bf1;
        #pragma unroll
        for (int j = 0; j < 8; j++) {
            float pA = fmaf(wa0[j],r0, fmaf(wa1[j],r1, fmaf(wa2[j],r2, ba[j])));
            bf0[j] = (_Float16)fmaxf(pA, 0.f);
            float pB = fmaf(wb0[j],r0, fmaf(wb1[j],r1, fmaf(wb2[j],r2, bb[j])));
            bf1[j] = (_Float16)fmaxf(pB, 0.f);
        }
        #pragma unroll
        for (int t = 0; t < 4; t++) {
            f32x4 acc = {0.f,0.f,0.f,0.f};
            acc = __builtin_amdgcn_mfma_f32_16x16x32_f16(afA[t], bf0, acc, 0, 0, 0);
            acc = __builtin_amdgcn_mfma_f32_16x16x32_f16(afB[t], bf1, acc, 0, 0, 0);
            #pragma unroll
            for (int r = 0; r < 4; r++) {
                float h = acc[r];
                int s = t*4 + r;
                mx[s]=fmaxf(mx[s],h); mn[s]=fminf(mn[s],h);
                sm[s]+=h;             sq[s]=fmaf(h,h,sq[s]);
            }
        }
    }
    #pragma unroll
    for (int m = 1; m < 16; m <<= 1) {
        #pragma unroll
        for (int s = 0; s < 16; s++) {
            mx[s] = fmaxf(mx[s], __shfl_xor(mx[s], m, 64));
            mn[s] = fminf(mn[s], __shfl_xor(mn[s], m, 64));
            sm[s] += __shfl_xor(sm[s], m, 64);
            sq[s] += __shfl_xor(sq[s], m, 64);
        }
    }
    __syncthreads();
    if (l15 == 0) {
        #pragma unroll
        for (int t = 0; t < 4; t++)
            #pragma unroll
            for (int r = 0; r < 4; r++) {
                int o = t*16 + quad*4 + r;
                redM[wv*64+o]=mx[t*4+r]; redN[wv*64+o]=mn[t*4+r];
                redS[wv*64+o]=sm[t*4+r]; redQ[wv*64+o]=sq[t*4+r];
            }
    }
    __syncthreads();
    float Mreg = -1e30f, Nreg = 1e30f;
    if (tid < 64) {
        float S=0.f, Q=0.f;
        #pragma unroll
        for (int w = 0; w < 4; w++) {
            Mreg = fmaxf(Mreg, redM[w*64+tid]); Nreg = fminf(Nreg, redN[w*64+tid]);
            S += redS[w*64+tid];               Q += redQ[w*64+tid];
        }
        atomicExch(&ws[WS_MAXV + bid*64 + tid], Mreg);
        atomicExch(&ws[WS_MINV + bid*64 + tid], Nreg);
        atomicExch(&ws[WS_BN1 + bid*128 + tid], S);
        atomicExch(&ws[WS_BN1 + bid*128 + 64 + tid], Q);
    }
    // ---- grid barrier 2 + BN1 reduce (plain loads, register accumulate) ----
    {
        __syncthreads();
        if (tid == 0)
            sflag[0] = (atomicAdd(&wsi[CNT_GRP + 1*32 + gi], 1) == 15) ? 1 : 0;
        __syncthreads();
        if (sflag[0]) {
            if (tid < 128) {
                float acc = 0.f;
                #pragma unroll
                for (int s = 0; s < 16; s++) acc += ws[WS_BN1 + (gb+s)*128 + tid];
                atomicExch(&ws[GBN1 + gi*128 + tid], acc);
            }
            __syncthreads();
            if (tid == 0)
                sflag[1] = (atomicAdd(&wsi[CNT_SUP + 1], 1) == 29) ? 1 : 0;
            __syncthreads();
            if (sflag[1]) {
                if (tid < 128) {
                    float acc = 0.f;
                    #pragma unroll
                    for (int s = 0; s < 30; s++) acc += ws[GBN1 + s*128 + tid];
                    atomicExch(&ws[FBN1 + tid], acc);
                }
                __syncthreads();
                if (tid == 0) atomicExch(&wsi[CNT_DONE + 1], 1);
            }
        }
        poll1<8>(&wsi[CNT_DONE + 1]);
    }

    // ---- T0: every block writes its lf1 column; stash s1/t1 in LDS ----
    if (tid < 64) {
        float SM = aloadf(&ws[FBN1 + tid]);
        float SQ = aloadf(&ws[FBN1 + 64 + tid]);
        float mean = SM / N1F;
        float var  = SQ / N1F - mean*mean;
        float s1 = g01[tid]*rsqrtf(var + EPS);
        float t1 = b01[tid] - mean*s1;
        sA[tid] = s1; tA[tid] = t1;
        float val = fmaxf(fmaf(s1, (s1 >= 0.f) ? Mreg : Nreg, t1), 0.f);
        out[8192 + b_*(67*GG) + (3+tid)*GG + g_] = val;
    }
    if (g_ != 0) return;               // 448 blocks done; 32 tail blocks continue
    __syncthreads();

    // ================= tail: stages 2+3 for batch b_, all in LDS ===============
    int b = b_;
    // f2: lf1 for all 15 g (plain loads of MAXV/MINV) + rel coords
    for (int idx = tid; idx < 960; idx += 256) {
        int g = idx >> 6, o = idx & 63, p = INV[g];
        float s1 = sA[o], t1 = tA[o];
        float sel = (s1 >= 0.f) ? ws[WS_MAXV + (b*GG+g)*64 + o]
                                : ws[WS_MINV + (b*GG+g)*64 + o];
        f2s[p*68 + 3 + o] = fmaxf(fmaf(s1, sel, t1), 0.f);
    }
    if (tid < 45) {
        int p = tid/3, i = tid%3;
        f2s[p*68 + i] = aloadf(&ws[WS_CENT + (b*GG + SIDX[p])*4 + i]) - c2ls[(p/3)*3 + i];
    }
    __syncthreads();

    int o = tid & 127, hf = tid >> 7;

    // ---- phase A: h2a = w10 @ f2 (15 pos split 8/7 across halves) ----
    {
        float accp[8] = {0,0,0,0,0,0,0,0};
        for (int c = 0; c < 67; c++) {
            float wv_ = w10[o*67 + c];
            #pragma unroll
            for (int pi = 0; pi < 8; pi++) {
                int p = hf*8 + pi;
                if (p < 15) accp[pi] = fmaf(wv_, f2s[p*68+c], accp[pi]);
            }
        }
        float smv=0.f, sqv=0.f;
        #pragma unroll
        for (int pi = 0; pi < 8; pi++) {
            int p = hf*8 + pi;
            if (p < 15) { float a=accp[pi]; h2a[p*132+o]=a; smv+=a; sqv=fmaf(a,a,sqv); }
        }
        redM[tid] = smv; redN[tid] = sqv;
        __syncthreads();
        if (tid < 128) {
            atomicExch(&ws[WS_P2A + b*256 + tid], redM[tid] + redM[tid+128]);
            atomicExch(&ws[WS_P2A + b*256 + 128 + tid], redN[tid] + redN[tid+128]);
        }
    }
    minibar<2>(wsi, 2, BB);
    // gather S2A (plain, unrolled) -> BN2a scale
    {
        float acc = 0.f;
        #pragma unroll
        for (int s = 0; s < 32; s++) acc += ws[WS_P2A + s*256 + tid];
        redM[tid] = acc;
        __syncthreads();
        if (tid < 128) {
            float mean = redM[tid] / 480.f;
            float var  = redM[128 + tid] / 480.f - mean*mean;
            float s2 = g10[tid]*rsqrtf(var + EPS);
            sC[tid] = s2; tC[tid] = b10[tid] - mean*s2;
        }
        __syncthreads();
    }
    // ---- phase B: v2 = relu(BN(h2a)) in place; h2b = w11 @ v2 ----
    for (int idx = tid; idx < 15*128; idx += 256) {
        int p = idx >> 7, oo = idx & 127;
        h2a[p*132+oo] = fmaxf(fmaf(sC[oo], h2a[p*132+oo], tC[oo]), 0.f);
    }
    __syncthreads();
    {
        float accp[8] = {0,0,0,0,0,0,0,0};
        for (int i = 0; i < 128; i++) {
            float wv_ = w11[o*128 + i];
            #pragma unroll
            for (int pi = 0; pi < 8; pi++) {
                int p = hf*8 + pi;
                if (p < 15) accp[pi] = fmaf(wv_, h2a[p*132+i], accp[pi]);
            }
        }
        float smv=0.f, sqv=0.f;
        #pragma unroll
        for (int pi = 0; pi < 8; pi++) {
            int p = hf*8 + pi;
            if (p < 15) { float a=accp[pi]; h2b[p*132+o]=a; smv+=a; sqv=fmaf(a,a,sqv); }
        }
        redM[tid] = smv; redN[tid] = sqv;
        __syncthreads();
        if (tid < 128) {
            atomicExch(&ws[WS_P2B + b*256 + tid], redM[tid] + redM[tid+128]);
            atomicExch(&ws[WS_P2B + b*256 + 128 + tid], redN[tid] + redN[tid+128]);
        }
    }
    minibar<2>(wsi, 3, BB);
    {
        float acc = 0.f;
        #pragma unroll
        for (int s = 0; s < 32; s++) acc += ws[WS_P2B + s*256 + tid];
        redM[tid] = acc;
        __syncthreads();
        if (tid < 128) {
            float mean = redM[tid] / 480.f;
            float var  = redM[128 + tid] / 480.f - mean*mean;
            float s3 = g11[tid]*rsqrtf(var + EPS);
            sC[tid] = s3; tC[tid] = b11[tid] - mean*s3;
        }
        __syncthreads();
    }
    // ---- phase C: lf2 + feats3; h3a = w20 @ f3 ----
    if (tid < 128) {
        for (int s5 = 0; s5 < 5; s5++) {
            float m = -1e30f;
            #pragma unroll
            for (int j = 0; j < 3; j++)
                m = fmaxf(m, fmaxf(fmaf(sC[tid], h2b[(s5*3+j)*132+tid], tC[tid]), 0.f));
            f3s[s5*132 + 3 + tid] = m;
        }
    } else if (tid < 143) {
        int t2 = tid - 128, s5 = t2/3, i = t2%3;
        f3s[s5*132 + i] = c2ls[s5*3+i] - c3ls[i];
    }
    __syncthreads();
    float acc5[5] = {0,0,0,0,0};
    {
        for (int c = 0; c < 131; c++) {
            float wv_ = w20[tid*131 + c];
            #pragma unroll
            for (int p = 0; p < 5; p++) acc5[p] = fmaf(wv_, f3s[p*132+c], acc5[p]);
        }
        __syncthreads();   // f2s/h2a regions dead; h3a aliases them
        float smv=0.f, sqv=0.f;
        #pragma unroll
        for (int p = 0; p < 5; p++) { float a=acc5[p]; h3a[p*260+tid]=a; smv+=a; sqv=fmaf(a,a,sqv); }
        atomicExch(&ws[WS_P3A + b*512 + tid], smv);
        atomicExch(&ws[WS_P3A + b*512 + 256 + tid], sqv);
    }
    minibar<2>(wsi, 4, BB);
    {
        float aS = 0.f, aQ = 0.f;
        #pragma unroll
        for (int s = 0; s < 32; s++) {
            aS += ws[WS_P3A + s*512 + tid];
            aQ += ws[WS_P3A + s*512 + 256 + tid];
        }
        float mean = aS / 160.f;
        float var  = aQ / 160.f - mean*mean;
        float s4 = g20[tid]*rsqrtf(var + EPS);
        sC3[tid] = s4; tC3[tid] = b20[tid] - mean*s4;
        __syncthreads();
    }
    // ---- phase D: v3 in place; h3b = w21 @ v3 (kept in registers) ----
    for (int idx = tid; idx < 5*256; idx += 256) {
        int p = idx >> 8, oo = idx & 255;
        h3a[p*260+oo] = fmaxf(fmaf(sC3[oo], h3a[p*260+oo], tC3[oo]), 0.f);
    }
    __syncthreads();
    {
        #pragma unroll
        for (int p = 0; p < 5; p++) acc5[p] = 0.f;
        for (int i = 0; i < 256; i++) {
            float wv_ = w21[tid*256 + i];
            #pragma unroll
            for (int p = 0; p < 5; p++) acc5[p] = fmaf(wv_, h3a[p*260+i], acc5[p]);
        }
        float smv=0.f, sqv=0.f;
        #pragma unroll
        for (int p = 0; p < 5; p++) { smv += acc5[p]; sqv = fmaf(acc5[p], acc5[p], sqv); }
        atomicExch(&ws[WS_P3B + b*512 + tid], smv);
        atomicExch(&ws[WS_P3B + b*512 + 256 + tid], sqv);
    }
    minibar<2>(wsi, 5, BB);
    // ---- phase E: gf = max_p relu(BN(h3b)) ----
    {
        float aS = 0.f, aQ = 0.f;
        #pragma unroll
        for (int s = 0; s < 32; s++) {
            aS += ws[WS_P3B + s*512 + tid];
            aQ += ws[WS_P3B + s*512 + 256 + tid];
        }
        float mean = aS / 160.f;
        float var  = aQ / 160.f - mean*mean;
        float s5c = g21[tid]*rsqrtf(var + EPS), t5 = b21[tid] - mean*s5c;
        float m = -1e30f;
        #pragma unroll
        for (int p = 0; p < 5; p++)
            m = fmaxf(m, fmaxf(fmaf(s5c, acc5[p], t5), 0.f));
        out[b*256 + tid] = m;
    }
}

extern "C" void kernel_launch(void* const* d_in, const int* in_sizes, int n_in,
                              void* d_out, int out_size, void* d_ws, size_t ws_size,
                              hipStream_t stream) {
    (void)in_sizes; (void)n_in; (void)out_size; (void)ws_size;
    const float* x   = (const float*)d_in[0];
    const float* w00 = (const float*)d_in[1];
    const float* g00 = (const float*)d_in[2];
    const float* b00 = (const float*)d_in[3];
    const float* w01 = (const float*)d_in[4];
    const float* g01 = (const float*)d_in[5];
    const float* b01 = (const float*)d_in[6];
    const float* w10 = (const float*)d_in[7];
    const float* g10 = (const float*)d_in[8];
    const float* b10 = (const float*)d_in[9];
    const float* w11 = (const float*)d_in[10];
    const float* g11 = (const float*)d_in[11];
    const float* b11 = (const float*)d_in[12];
    const float* w20 = (const float*)d_in[13];
    const float* g20 = (const float*)d_in[14];
    const float* b20 = (const float*)d_in[15];
    const float* w21 = (const float*)d_in[16];
    const float* g21 = (const float*)d_in[17];
    const float* b21 = (const float*)d_in[18];
    float* out = (float*)d_out;
    float* ws  = (float*)d_ws;

    mega<<<NB, 256, 0, stream>>>(x, w00,g00,b00, w01,g01,b01, w10,g10,b10,
                                 w11,g11,b11, w20,g20,b20, w21,g21,b21, ws, out);
}